// Round 2
// 110.319 us; speedup vs baseline: 1.0627x; 1.0627x over previous
//
#include <hip/hip_runtime.h>

#define T 8
#define VTH 1.0f
#define BN_EPS 1e-5f
#define CG 8           // channels per K1 block (fully unrolled -> s_loads hoisted)
#define NG (128 / CG)  // channel groups

// Spike-pattern LUT for IF with constant drive p and hard reset to exact 0:
// inter-spike interval n = first t (1-indexed) with iterated prefix sum >= VTH.
// byte[n-1] = bitmask of fire steps (t = n, 2n, 3n, ... <= 8), 0-indexed bits.
// n: 1->0xFF 2->0xAA 3->0x24 4->0x88 5->0x10 6->0x20 7->0x40 8->0x80
#define IF_LUT 0x804020108824AAFFull

// Kernel 1: conv3x3(pad=1) + BN(eval) + IF(8 steps, hard reset) + maxpool2x2(OR)
// One block per (image-pair, channel-group). 448 threads; tid<392 active,
// lanes split 196+196 across the two images (87.5% lane utilization).
__global__ __launch_bounds__(448) void k_conv_if_pool(
    const float* __restrict__ x,       // [128,1,28,28]
    const float* __restrict__ conv_w,  // [128,1,3,3]
    const float* __restrict__ gamma,   // [128]
    const float* __restrict__ beta,    // [128]
    const float* __restrict__ mean,    // [128]
    const float* __restrict__ var,     // [128]
    unsigned char* __restrict__ f)     // [128,128,196] bitmasks
{
    __shared__ float xs[2][30 * 30];   // two zero-padded input images
    const int blk = blockIdx.x;        // bp*NG + g
    const int bp = blk / NG;           // image pair index (0..63)
    const int g = blk - bp * NG;
    const int tid = threadIdx.x;

    for (int i = tid; i < 900; i += 448) { xs[0][i] = 0.0f; xs[1][i] = 0.0f; }
    __syncthreads();
    const float* xb = x + bp * 1568;   // two consecutive images
    for (int i = tid; i < 1568; i += 448) {
        const int bl = (i >= 784) ? 1 : 0;
        const int j = i - bl * 784;
        const int h = j / 28, w = j - h * 28;
        xs[bl][(h + 1) * 30 + (w + 1)] = xb[i];
    }
    __syncthreads();

    if (tid >= 392) return;
    const int bl = (tid >= 196) ? 1 : 0;
    const int pos = tid - bl * 196;
    const int ph = pos / 14, pw = pos - ph * 14;
    const int b = bp * 2 + bl;

    // 4x4 input patch for this pooled position (both conv cells + halo)
    float patch[16];
    {
        const float* xr = &xs[bl][(2 * ph) * 30 + 2 * pw];
        #pragma unroll
        for (int r = 0; r < 4; r++)
            #pragma unroll
            for (int cc = 0; cc < 4; cc++)
                patch[r * 4 + cc] = xr[r * 30 + cc];
    }

    unsigned char* frow = f + (b * 128 + g * CG) * 196 + pos;

    #pragma unroll
    for (int ci = 0; ci < CG; ci++) {
        const int c = g * CG + ci;
        const float* wc = conv_w + c * 9;   // uniform -> scalar loads, hoisted
        float wv[9];
        #pragma unroll
        for (int i = 0; i < 9; i++) wv[i] = wc[i];
        const float sc = gamma[c] * rsqrtf(var[c] + BN_EPS);
        const float sh = beta[c] - mean[c] * sc;   // pre = y*sc + sh

        // conv for the 4 cells of this pooled position
        float p[4];
        #pragma unroll
        for (int dy = 0; dy < 2; dy++)
            #pragma unroll
            for (int dx = 0; dx < 2; dx++) {
                float y = 0.0f;
                #pragma unroll
                for (int kh = 0; kh < 3; kh++)
                    #pragma unroll
                    for (int kw = 0; kw < 3; kw++)
                        y += patch[(dy + kh) * 4 + (dx + kw)] * wv[kh * 3 + kw];
                p[dy * 2 + dx] = y * sc + sh;
            }

        // IF over 8 steps, closed-form via first-passage count.
        // Exact: reset to 0.0f makes every inter-spike interval identical to
        // the first passage of the iterated (rounded) prefix sum past VTH,
        // and (v - VTH >= 0) <=> (v >= VTH) for finite v.
        unsigned int bits = 0;
        #pragma unroll
        for (int cell = 0; cell < 4; cell++) {
            float s = 0.0f;
            int cnt = 0;                       // #steps with prefix sum < VTH
            #pragma unroll
            for (int t = 0; t < T; t++) {
                s += p[cell];
                cnt += (s < VTH) ? 1 : 0;      // monotone set for p>0; p<=0 -> 8
            }
            const unsigned int bm = (cnt >= 8) ? 0u
                : (unsigned int)((IF_LUT >> ((cnt & 7) * 8)) & 0xFFull);
            bits |= bm;                        // pool == OR of cell masks
        }
        frow[ci * 196] = (unsigned char)bits;
    }
}

// Kernel 2: one block per (b, output-group of 5). 1024 threads (16 waves/CU
// -> 4 waves/SIMD for latency hiding of the L2-resident weight streams).
__global__ __launch_bounds__(1024) void k_fc_if(
    const unsigned char* __restrict__ f,   // [128, 25088]
    const float* __restrict__ fc_w,        // [10, 25088]
    float* __restrict__ out)               // [128, 10]
{
    const int blk = blockIdx.x;            // b*2 + og
    const int b = blk >> 1;
    const int og = blk & 1;                // outputs og*5 .. og*5+4
    const int tid = threadIdx.x;
    const int lane = tid & 63;
    const int wave = tid >> 6;             // 0..15

    const unsigned int* fm = (const unsigned int*)(f + b * 25088);
    const float4* fw0 = (const float4*)(fc_w + (og * 5 + 0) * 25088);
    const float4* fw1 = (const float4*)(fc_w + (og * 5 + 1) * 25088);
    const float4* fw2 = (const float4*)(fc_w + (og * 5 + 2) * 25088);
    const float4* fw3 = (const float4*)(fc_w + (og * 5 + 3) * 25088);
    const float4* fw4 = (const float4*)(fc_w + (og * 5 + 4) * 25088);

    float acc[T][5];
    #pragma unroll
    for (int t = 0; t < T; t++)
        #pragma unroll
        for (int o = 0; o < 5; o++) acc[t][o] = 0.0f;

    for (int i = tid; i < 25088 / 4; i += 1024) {
        const unsigned int m4 = fm[i];
        float4 w[5] = {fw0[i], fw1[i], fw2[i], fw3[i], fw4[i]};
        #pragma unroll
        for (int j = 0; j < 4; j++) {
            const float wj[5] = {((const float*)&w[0])[j], ((const float*)&w[1])[j],
                                 ((const float*)&w[2])[j], ((const float*)&w[3])[j],
                                 ((const float*)&w[4])[j]};
            #pragma unroll
            for (int t = 0; t < T; t++) {
                const float bit = (float)((m4 >> (8 * j + t)) & 1u);  // bfe+cvt
                #pragma unroll
                for (int o = 0; o < 5; o++)
                    acc[t][o] = fmaf(bit, wj[o], acc[t][o]);  // exact: +w or +0
            }
        }
    }

    __shared__ float red[16][T * 5];
    #pragma unroll
    for (int t = 0; t < T; t++)
        #pragma unroll
        for (int o = 0; o < 5; o++) {
            float v = acc[t][o];
            #pragma unroll
            for (int off = 32; off > 0; off >>= 1)
                v += __shfl_down(v, off, 64);
            if (lane == 0) red[wave][t * 5 + o] = v;
        }
    __syncthreads();

    __shared__ float tot[T * 5];
    if (tid < T * 5) {
        float s = 0.0f;
        #pragma unroll
        for (int wv = 0; wv < 16; wv++) s += red[wv][tid];
        tot[tid] = s;
    }
    __syncthreads();

    if (tid < 5) {
        float v2 = 0.0f, cnt = 0.0f;
        #pragma unroll
        for (int t = 0; t < T; t++) {
            v2 += tot[t * 5 + tid];
            if (v2 - VTH >= 0.0f) { cnt += 1.0f; v2 = 0.0f; }
        }
        out[b * 10 + og * 5 + tid] = cnt * (1.0f / (float)T);
    }
}

extern "C" void kernel_launch(void* const* d_in, const int* in_sizes, int n_in,
                              void* d_out, int out_size, void* d_ws, size_t ws_size,
                              hipStream_t stream) {
    const float* x      = (const float*)d_in[0];  // [128,1,28,28]
    const float* conv_w = (const float*)d_in[1];  // [128,1,3,3]
    const float* gamma  = (const float*)d_in[2];
    const float* beta   = (const float*)d_in[3];
    const float* mean   = (const float*)d_in[4];
    const float* var    = (const float*)d_in[5];
    const float* fc_w   = (const float*)d_in[6];  // [10, 25088]
    float* out = (float*)d_out;                    // [128,10]

    unsigned char* f = (unsigned char*)d_ws;       // 128*25088 = 3.2 MB bitmasks

    k_conv_if_pool<<<64 * NG, 448, 0, stream>>>(x, conv_w, gamma, beta, mean, var, f);
    k_fc_if<<<128 * 2, 1024, 0, stream>>>(f, fc_w, out);
}